// Round 11
// baseline (2187.203 us; speedup 1.0000x reference)
//
#include <hip/hip_runtime.h>
#include <hip/hip_bf16.h>

#define VOCAB  32000
#define EMBED  512
#define HIDDEN 1024
#define BATCH  16
#define SEQ    256
#define NROW   (BATCH*SEQ)
#define GCOLS  (4*HIDDEN)
#define NWREC  64
#define NWPACK 192
#define NTILE  8000          // 8 rounds x (250 bn x 4 bm)
#define SENT32 0xFFFFFFFFu

typedef unsigned short u16;
typedef unsigned int   u32;
typedef unsigned long long u64;
typedef __attribute__((ext_vector_type(4))) float f32x4;
typedef __attribute__((ext_vector_type(8))) short bf16x8;
typedef __attribute__((ext_vector_type(8))) unsigned short u16x8;
typedef __attribute__((ext_vector_type(2))) unsigned long long u64x2;

__device__ inline u16 f2bf(float f){
  __hip_bfloat16 h = __float2bfloat16(f);
  return __builtin_bit_cast(u16, h);
}
__device__ inline void gload_lds16(const void* g, void* l){
  __builtin_amdgcn_global_load_lds((const __attribute__((address_space(1))) u32*)g,
                                   (__attribute__((address_space(3))) u32*)l, 16, 0, 0);
}
__device__ __forceinline__ u32 al32(const u32* p){
  return __hip_atomic_load(p, __ATOMIC_RELAXED, __HIP_MEMORY_SCOPE_AGENT);
}
__device__ __forceinline__ u64 al64(const u64* p){
  return __hip_atomic_load(p, __ATOMIC_RELAXED, __HIP_MEMORY_SCOPE_AGENT);
}
__device__ __forceinline__ void as32(u32* p, u32 v){
  __hip_atomic_store(p, v, __ATOMIC_RELAXED, __HIP_MEMORY_SCOPE_AGENT);
}
__device__ __forceinline__ void as64(u64* p, u64 v){
  __hip_atomic_store(p, v, __ATOMIC_RELAXED, __HIP_MEMORY_SCOPE_AGENT);
}

// ---------------------------------------------------------------------------
__global__ __launch_bounds__(256) void pack_gates(
    const float* __restrict__ Wf, const float* __restrict__ Wi,
    const float* __restrict__ Wc, const float* __restrict__ Wo,
    const float* __restrict__ bf_, const float* __restrict__ bi_,
    const float* __restrict__ bc_, const float* __restrict__ bo_,
    u16* __restrict__ Wxp, u16* __restrict__ Whp, float* __restrict__ bcat)
{
  const int NT_WX = (GCOLS/16)*(EMBED/32)*64;
  const int NT_WH = (GCOLS/16)*(HIDDEN/32)*64;
  int t = blockIdx.x*256 + threadIdx.x;
  if (t < NT_WX){
    int u = t;
    int lane = u&63; int kb = (u>>6)&15; int nblk = u>>10;
    int col = nblk*16 + (lane&15);
    int k0  = kb*32 + ((lane>>4)<<3);
    int g = col>>10, j = col&1023;
    const float* W = (g==0)?Wf:(g==1)?Wi:(g==2)?Wc:Wo;
    u16x8 v;
    #pragma unroll
    for (int e=0;e<8;e++) v[e] = f2bf(W[(size_t)(k0+e)*HIDDEN + j]);
    *(u16x8*)(Wxp + (size_t)u*8) = v;
  } else if (t < NT_WX + NT_WH){
    int u = t - NT_WX;
    int lane = u&63; int kb = (u>>6)&31; int nblk = u>>11;
    int col = nblk*16 + (lane&15);
    int k0  = kb*32 + ((lane>>4)<<3);
    int g = col>>10, j = col&1023;
    const float* W = (g==0)?Wf:(g==1)?Wi:(g==2)?Wc:Wo;
    u16x8 v;
    #pragma unroll
    for (int e=0;e<8;e++) v[e] = f2bf(W[(size_t)(EMBED + k0+e)*HIDDEN + j]);
    *(u16x8*)(Whp + (size_t)u*8) = v;
  } else {
    int u = t - NT_WX - NT_WH;
    if (u < GCOLS){
      int g = u>>10, j = u&1023;
      const float* B = (g==0)?bf_:(g==1)?bi_:(g==2)?bc_:bo_;
      bcat[u] = B[j];
    }
  }
}

// ---------------------------------------------------------------------------
__global__ __launch_bounds__(256) void gather_kernel(
    const int* __restrict__ tok, const float* __restrict__ embed, u16* __restrict__ Xg)
{
  int t = blockIdx.x*256 + threadIdx.x;
  int lane = t&63; int kb = (t>>6)&15; int mblk = t>>10;
  int s = mblk; int b = lane&15;
  int token = tok[b*SEQ + s];
  int k0 = kb*32 + ((lane>>4)<<3);
  const float* src = embed + (size_t)token*EMBED + k0;
  u16x8 v;
  #pragma unroll
  for (int e=0;e<8;e++) v[e] = f2bf(src[e]);
  *(u16x8*)(Xg + (size_t)t*8) = v;
}

// ---------------------------------------------------------------------------
template<int KB, bool REMAP>
__global__ __launch_bounds__(256,2) void gemm_pk(
    const u16* __restrict__ Ap, const u16* __restrict__ Bp,
    const float* __restrict__ bias, float* __restrict__ C,
    int Nblk128, int N)
{
  __shared__ u16 sm[8192];
  int tid = threadIdx.x; int lane = tid&63; int wv = tid>>6;
  int nwg = gridDim.x;
  int bid = blockIdx.x;
  int swz = (bid&7)*(nwg>>3) + (bid>>3);
  int bm = swz / Nblk128, bn = swz % Nblk128;
  int wr = wv>>1, wc = wv&1;
  f32x4 acc[4][4] = {};
  const u16* Abase = Ap + (size_t)(bm*8)*KB*512;
  const u16* Bbase = Bp + (size_t)(bn*8)*KB*512;
  for (int kb=0; kb<KB; ++kb){
    __syncthreads();
    #pragma unroll
    for (int c2=0;c2<4;c2++){
      int chunk = wv*4 + c2;
      const u16* g;
      if (chunk < 8) g = Abase + ((size_t)chunk*KB + kb)*512 + lane*8;
      else           g = Bbase + ((size_t)(chunk-8)*KB + kb)*512 + lane*8;
      gload_lds16(g, sm + chunk*512);
    }
    __syncthreads();
    bf16x8 a[4], b[4];
    #pragma unroll
    for (int m=0;m<4;m++) a[m] = *(const bf16x8*)(sm + (wr*4+m)*512 + lane*8);
    #pragma unroll
    for (int n=0;n<4;n++) b[n] = *(const bf16x8*)(sm + 4096 + (wc*4+n)*512 + lane*8);
    #pragma unroll
    for (int m=0;m<4;m++)
      #pragma unroll
      for (int n=0;n<4;n++)
        acc[m][n] = __builtin_amdgcn_mfma_f32_16x16x32_bf16(a[m], b[n], acc[m][n], 0,0,0);
  }
  int colb = bn*128 + wc*64;
  int rowb = bm*128 + wr*64;
  #pragma unroll
  for (int m=0;m<4;m++){
    int row0 = rowb + m*16 + (lane>>4)*4;
    #pragma unroll
    for (int n=0;n<4;n++){
      int col = colb + n*16 + (lane&15);
      float bv = bias[col];
      #pragma unroll
      for (int r2=0;r2<4;r2++){
        int row = row0 + r2;
        int orow = REMAP ? ((row&15)*SEQ + (row>>4)) : row;
        C[(size_t)orow*N + col] = acc[m][n][r2] + bv;
      }
    }
  }
}

// ---------------------------------------------------------------------------
// FUSED kernel. Recurrence exchange = PRIVATE MAILBOXES:
//   mbox[slot(2)][consumer(64)][32KB] — every cache line has exactly one
//   writer wave and one reader WG (no TCC same-line contention, the r7-r10
//   invariant 4.2us/step pacer). Producer broadcasts its 512B h-slice to all
//   64 consumer replicas (32 u32 stores/thread). Slot reuse (double buffer)
//   guarded by consumer re-sentinel + a ~free vmcnt(0) before the h stores.
// ---------------------------------------------------------------------------
__global__ __launch_bounds__(256,1) void lstm_fused(
    const u16* __restrict__ Whp, const float* __restrict__ Xpre,
    u16* mbox, u16* Hp, u32* cnt, u32* tix, u32* packdone,
    const float* __restrict__ Wout, u16* __restrict__ Woutp,
    const float* __restrict__ bout, float* __restrict__ out)
{
  __shared__ char SMEM[148480];
  __shared__ u32 s_tick;
  u16* smWf = (u16*)SMEM;
  float (*gl)[16][17] = (float (*)[16][17])(SMEM + 131072);
  u16* smg = (u16*)SMEM;             // GEMM phase: 3 x 16KB buffers

  int tid = threadIdx.x; int lane = tid&63; int v = tid>>6;
  int w = blockIdx.x;

  if (w >= NWREC){
    // ---------------- Wout pack (L3-direct stores) ------------------------
    const int NPK = (VOCAB/16)*(HIDDEN/32)*64;
    int u0 = (w - NWREC)*256 + tid;
    for (int u = u0; u < NPK; u += NWPACK*256){
      int l = u&63; int kb = (u>>6)&31; int nblk = u>>11;
      int col = nblk*16 + (l&15);
      int k0  = kb*32 + ((l>>4)<<3);
      u16x8 vv;
      #pragma unroll
      for (int e=0;e<8;e++) vv[e] = f2bf(Wout[(size_t)(k0+e)*VOCAB + col]);
      u64x2 t2 = __builtin_bit_cast(u64x2, vv);
      u64* dst = (u64*)(Woutp + (size_t)u*8);
      as64(dst+0, t2[0]);
      as64(dst+1, t2[1]);
    }
    asm volatile("s_waitcnt vmcnt(0)" ::: "memory");
    __syncthreads();
    if (tid==0) (void)__hip_atomic_fetch_add(packdone, 1u,
                       __ATOMIC_RELAXED, __HIP_MEMORY_SCOPE_AGENT);
  } else {
    // ---------------- recurrence ------------------------------------------
    #pragma unroll
    for (int f=0; f<32; ++f){
      int frag = v*32 + f;
      int g = frag>>5, kc = frag&31;
      const u16* src = Whp + ((size_t)(g*64 + w)*32 + kc)*512 + lane*8;
      gload_lds16(src, smWf + (size_t)frag*512);
    }
    asm volatile("s_waitcnt vmcnt(0)" ::: "memory");
    __syncthreads();

    float c = 0.f;
    int pb = tid>>4, pj = tid&15;
    int j = w*16 + pj;
    const int a_row = lane&15, a_k = (lane>>4)*8;
    const float* xb0 = Xpre + (size_t)pb*GCOLS + j;
    float x0 = xb0[0], x1 = xb0[1024], x2 = xb0[2048], x3 = xb0[3072];

    for (int s=0;s<SEQ;s++){
      // A. poll MY private mailbox, slot (s-1)&1 == (s+1)&1
      const u16* rb = mbox + (size_t)((s+1)&1)*1048576 + (size_t)w*16384;
      u64 vv[16];
      for(;;){
        #pragma unroll
        for (int i=0;i<16;i++){
          const u64* p = (const u64*)(rb + a_row*1024 + (v*8+(i>>1))*32 + a_k) + (i&1);
          vv[i] = al64(p);
        }
        bool ok = true;
        #pragma unroll
        for (int i=0;i<16;i++)
          ok &= ((u32)vv[i]!=SENT32) & ((u32)(vv[i]>>32)!=SENT32);
        if (ok) break;
        __builtin_amdgcn_s_sleep(1);
      }
      // B. re-sentinel my region (slot will next carry h_{s+1})
      if (s < SEQ-1){
        #pragma unroll
        for (int i=0;i<16;i++){
          u64* p = (u64*)(rb + a_row*1024 + (v*8+(i>>1))*32 + a_k) + (i&1);
          as64(p, ~0ull);
        }
      }
      // C. x prefetch for s+1 (drains at G)
      float xn0=0.f,xn1=0.f,xn2=0.f,xn3=0.f;
      if (s < SEQ-1){
        const float* xn = Xpre + ((size_t)(s+1)*16 + pb)*GCOLS + j;
        xn0 = xn[0]; xn1 = xn[1024]; xn2 = xn[2048]; xn3 = xn[3072];
      }
      // D. MFMA
      bf16x8 af[8];
      #pragma unroll
      for (int i=0;i<8;i++){
        u64x2 t2 = {vv[2*i], vv[2*i+1]};
        af[i] = __builtin_bit_cast(bf16x8, t2);
      }
      f32x4 acc[4] = {};
      #pragma unroll
      for (int i=0;i<8;i++){
        #pragma unroll
        for (int g=0;g<4;g++){
          bf16x8 wfv = *(const bf16x8*)(smWf + ((size_t)(g*32 + v*8 + i))*512 + lane*8);
          acc[g] = __builtin_amdgcn_mfma_f32_16x16x32_bf16(af[i], wfv, acc[g], 0,0,0);
        }
      }
      {
        int jj = lane&15, b0 = (lane>>4)*4;
        #pragma unroll
        for (int g=0;g<4;g++)
          #pragma unroll
          for (int r2=0;r2<4;r2++)
            gl[v*4+g][b0+r2][jj] = acc[g][r2];
      }
      // E. B1: LDS drain + raw barrier
      asm volatile("s_waitcnt lgkmcnt(0)" ::: "memory");
      __builtin_amdgcn_s_barrier();
      __builtin_amdgcn_sched_barrier(0);
      // F. pointwise
      float p0 = x0 + gl[0][pb][pj] + gl[4][pb][pj] + gl[ 8][pb][pj] + gl[12][pb][pj];
      float p1 = x1 + gl[1][pb][pj] + gl[5][pb][pj] + gl[ 9][pb][pj] + gl[13][pb][pj];
      float p2 = x2 + gl[2][pb][pj] + gl[6][pb][pj] + gl[10][pb][pj] + gl[14][pb][pj];
      float p3 = x3 + gl[3][pb][pj] + gl[7][pb][pj] + gl[11][pb][pj] + gl[15][pb][pj];
      float fg = 1.f/(1.f+__expf(-p0));
      float ig = 1.f/(1.f+__expf(-p1));
      float e2 = __expf(2.f*fminf(fmaxf(p2,-15.f),15.f));
      float cand = (e2-1.f)/(e2+1.f);
      float og = 1.f/(1.f+__expf(-p3));
      c = c*fg + cand*ig;
      float h = c*og;
      x0 = xn0; x1 = xn1; x2 = xn2; x3 = xn3;
      // G. drain re-sentinels (+xn) BEFORE publishing h — ~free (0.5us old)
      asm volatile("s_waitcnt vmcnt(0)" ::: "memory");
      // H. broadcast h to all 64 consumer replicas + Hp store
      u32 hb16 = (u32)f2bf(h);
      u32 nb   = (u32)__shfl_xor((int)hb16, 1);
      u32 word = (pj&1) ? ((hb16<<16) | nb) : (hb16 | (nb<<16));
      if (s < SEQ-1){
        u32* mb = (u32*)mbox + (size_t)(s&1)*524288
                + (size_t)pb*512 + w*8 + (pj>>1);
        int c0 = (pj&1) ? 32 : 0;     // pair splits the 64 consumers
        #pragma unroll
        for (int cc=0; cc<32; cc++){
          int cdst = c0 + ((w + cc) & 31);
          as32(mb + (size_t)cdst*8192, word);
        }
      }
      if ((pj&1)==0){
        as32((u32*)Hp + (size_t)s*8192 + (size_t)(j>>5)*256
                      + (size_t)(((j>>3)&3)*16 + pb)*4 + ((j&7)>>1), word);
      }
      // I. B2: raw barrier (gl WAR)
      __builtin_amdgcn_s_barrier();
      __builtin_amdgcn_sched_barrier(0);
      // J. per-8-step GEMM gating bookkeeping
      if ((s&7)==7){
        asm volatile("s_waitcnt vmcnt(0)" ::: "memory");
        __builtin_amdgcn_s_barrier();
        asm volatile("" ::: "memory");
        if (tid==0)
          (void)__hip_atomic_fetch_add(cnt + (size_t)(s>>3)*16, 1u,
                   __ATOMIC_RELAXED, __HIP_MEMORY_SCOPE_AGENT);
      }
    }
  }

  // ---------------- logits-GEMM worker pool -------------------------------
  if (tid==0){
    while (al32(packdone) < (u32)NWPACK) __builtin_amdgcn_s_sleep(8);
  }
  __syncthreads();

  int wv = tid>>6;
  int wr = wv>>1, wc = wv&1;
  for(;;){
    __syncthreads();
    if (tid==0) s_tick = __hip_atomic_fetch_add(tix, 1u,
                   __ATOMIC_RELAXED, __HIP_MEMORY_SCOPE_AGENT);
    __syncthreads();
    u32 t = s_tick;
    if (t >= (u32)NTILE) break;
    // 8 rounds of (250 bn x 4 bm): Woutp panel streams 8x not 32x
    u32 rr = t / 1000u, local = t % 1000u;
    int bn = (int)(local >> 2);
    int bm = (int)(rr*4u + (local & 3u));
    if (tid==0){
      while (al32(cnt + (size_t)bm*16) < (u32)NWREC)
        __builtin_amdgcn_s_sleep(8);
    }
    __syncthreads();                                 // full drain (vm+lgkm)
    const u16* Ab = Hp + (size_t)(bm*8)*32*512;
    const u16* Bb = Woutp + (size_t)(bn*8)*32*512;
    auto stage = [&](int kb, int bi){
      #pragma unroll
      for (int c2=0;c2<4;c2++){
        int chunk = wv*4 + c2;
        const u16* g;
        if (chunk < 8) g = Ab + ((size_t)chunk*32 + kb)*512 + lane*8;
        else           g = Bb + ((size_t)(chunk-8)*32 + kb)*512 + lane*8;
        gload_lds16(g, smg + (size_t)bi*8192 + chunk*512);
      }
    };
    stage(0,0); stage(1,1);
    f32x4 acc[4][4] = {};
    for (int kb=0; kb<32; ++kb){
      if (kb<31) asm volatile("s_waitcnt vmcnt(4)" ::: "memory");
      else       asm volatile("s_waitcnt vmcnt(0)" ::: "memory");
      __builtin_amdgcn_s_barrier();                  // raw: loads stay in flight
      if (kb+2<32) stage(kb+2, (kb+2)%3);
      const u16* bufp = smg + (size_t)(kb%3)*8192;
      bf16x8 a[4], b[4];
      #pragma unroll
      for (int m=0;m<4;m++) a[m] = *(const bf16x8*)(bufp + (wr*4+m)*512 + lane*8);
      #pragma unroll
      for (int n=0;n<4;n++) b[n] = *(const bf16x8*)(bufp + 4096 + (wc*4+n)*512 + lane*8);
      #pragma unroll
      for (int m=0;m<4;m++)
        #pragma unroll
        for (int n=0;n<4;n++)
          acc[m][n] = __builtin_amdgcn_mfma_f32_16x16x32_bf16(a[m], b[n], acc[m][n], 0,0,0);
    }
    int colb = bn*128 + wc*64;
    int rowb = bm*128 + wr*64;
    #pragma unroll
    for (int m=0;m<4;m++){
      int row0 = rowb + m*16 + (lane>>4)*4;
      #pragma unroll
      for (int n=0;n<4;n++){
        int col = colb + n*16 + (lane&15);
        float bv = bout[col];
        #pragma unroll
        for (int r2=0;r2<4;r2++){
          int row = row0 + r2;
          int orow = (row&15)*SEQ + (row>>4);
          __builtin_nontemporal_store(acc[m][n][r2] + bv,
                                      &out[(size_t)orow*VOCAB + col]);
        }
      }
    }
  }
}

// ---------------------------------------------------------------------------
extern "C" void kernel_launch(void* const* d_in, const int* in_sizes, int n_in,
                              void* d_out, int out_size, void* d_ws, size_t ws_size,
                              hipStream_t stream)
{
  (void)in_sizes; (void)n_in; (void)out_size; (void)ws_size;
  const int*   tok   = (const int*)d_in[0];
  const float* embed = (const float*)d_in[1];
  const float* Wf    = (const float*)d_in[2];
  const float* bf_   = (const float*)d_in[3];
  const float* Wi    = (const float*)d_in[4];
  const float* bi_   = (const float*)d_in[5];
  const float* Wc    = (const float*)d_in[6];
  const float* bc_   = (const float*)d_in[7];
  const float* Wo    = (const float*)d_in[8];
  const float* bo_   = (const float*)d_in[9];
  const float* Wout  = (const float*)d_in[10];
  const float* bout  = (const float*)d_in[11];
  float* out = (float*)d_out;

  char* ws = (char*)d_ws;
  size_t off = 0;
  auto alloc = [&](size_t bytes)->void*{
    void* p = ws + off; off += (bytes + 255) & ~(size_t)255; return p;
  };
  // dead-after-gemm16 region; mbox aliases it (memset AFTER gemm16):
  u16*  Wxp   = (u16*)alloc((size_t)2097152*2);        // 4 MB
  u16*  Xg    = (u16*)alloc((size_t)2097152*2);        // 4 MB
  float* bcat = (float*)alloc((size_t)4096*4);         // 16 KB
  u16*  mbox  = (u16*)ws;                              // 2 slots x 64 x 32KB = 4 MB
  // live-through-fused region:
  u16*  Whp   = (u16*)alloc((size_t)4194304*2);        // 8 MB
  u16*  Woutp = (u16*)alloc((size_t)32768000*2);       // 65.5 MB
  float* Xpre = (float*)alloc((size_t)NROW*GCOLS*4);   // 64 MB
  u16*  Hp    = (u16*)alloc((size_t)4194304*2);        // 8 MB
  u32*  cnt   = (u32*)alloc((size_t)4096);             // 32 bm x 64B
  u32*  tix   = (u32*)alloc((size_t)256);
  u32*  packdone = (u32*)alloc((size_t)256);

  pack_gates<<<3088, 256, 0, stream>>>(Wf,Wi,Wc,Wo, bf_,bi_,bc_,bo_,
                                       Wxp, Whp, bcat);
  gather_kernel<<<1024, 256, 0, stream>>>(tok, embed, Xg);
  gemm_pk<16,false><<<1024, 256, 0, stream>>>(Xg, Wxp, bcat, Xpre, 32, GCOLS);
  // mbox aliases Wxp/Xg -> init only after gemm16:
  (void)hipMemsetAsync(mbox, 0xFF, 2097152, stream);                  // slot 0: sentinel
  (void)hipMemsetAsync((char*)mbox + 2097152, 0x00, 2097152, stream); // slot 1: h_{-1}=0
  (void)hipMemsetAsync(cnt, 0, 4096 + 256 + 256, stream);
  lstm_fused<<<NWREC+NWPACK, 256, 0, stream>>>(Whp, Xpre, mbox, Hp, cnt, tix,
                                               packdone, Wout, Woutp, bout, out);
}

// Round 12
// 1451.825 us; speedup vs baseline: 1.5065x; 1.5065x over previous
//
#include <hip/hip_runtime.h>
#include <hip/hip_bf16.h>

#define VOCAB  32000
#define EMBED  512
#define HIDDEN 1024
#define BATCH  16
#define SEQ    256
#define NROW   (BATCH*SEQ)
#define GCOLS  (4*HIDDEN)
#define NWREC  64
#define NWPACK 192
#define NTILE  8000          // 8 rounds x (250 bn x 4 bm)
#define SENT32 0xFFFFFFFFu

typedef unsigned short u16;
typedef unsigned int   u32;
typedef unsigned long long u64;
typedef __attribute__((ext_vector_type(4))) float f32x4;
typedef __attribute__((ext_vector_type(8))) short bf16x8;
typedef __attribute__((ext_vector_type(8))) unsigned short u16x8;
typedef __attribute__((ext_vector_type(2))) unsigned long long u64x2;

__device__ inline u16 f2bf(float f){
  __hip_bfloat16 h = __float2bfloat16(f);
  return __builtin_bit_cast(u16, h);
}
__device__ inline void gload_lds16(const void* g, void* l){
  __builtin_amdgcn_global_load_lds((const __attribute__((address_space(1))) u32*)g,
                                   (__attribute__((address_space(3))) u32*)l, 16, 0, 0);
}
__device__ __forceinline__ u32 al32(const u32* p){
  return __hip_atomic_load(p, __ATOMIC_RELAXED, __HIP_MEMORY_SCOPE_AGENT);
}
__device__ __forceinline__ u64 al64(const u64* p){
  return __hip_atomic_load(p, __ATOMIC_RELAXED, __HIP_MEMORY_SCOPE_AGENT);
}
__device__ __forceinline__ void as32(u32* p, u32 v){
  __hip_atomic_store(p, v, __ATOMIC_RELAXED, __HIP_MEMORY_SCOPE_AGENT);
}
__device__ __forceinline__ void as64(u64* p, u64 v){
  __hip_atomic_store(p, v, __ATOMIC_RELAXED, __HIP_MEMORY_SCOPE_AGENT);
}

// ---------------------------------------------------------------------------
__global__ __launch_bounds__(256) void pack_gates(
    const float* __restrict__ Wf, const float* __restrict__ Wi,
    const float* __restrict__ Wc, const float* __restrict__ Wo,
    const float* __restrict__ bf_, const float* __restrict__ bi_,
    const float* __restrict__ bc_, const float* __restrict__ bo_,
    u16* __restrict__ Wxp, u16* __restrict__ Whp, float* __restrict__ bcat)
{
  const int NT_WX = (GCOLS/16)*(EMBED/32)*64;
  const int NT_WH = (GCOLS/16)*(HIDDEN/32)*64;
  int t = blockIdx.x*256 + threadIdx.x;
  if (t < NT_WX){
    int u = t;
    int lane = u&63; int kb = (u>>6)&15; int nblk = u>>10;
    int col = nblk*16 + (lane&15);
    int k0  = kb*32 + ((lane>>4)<<3);
    int g = col>>10, j = col&1023;
    const float* W = (g==0)?Wf:(g==1)?Wi:(g==2)?Wc:Wo;
    u16x8 v;
    #pragma unroll
    for (int e=0;e<8;e++) v[e] = f2bf(W[(size_t)(k0+e)*HIDDEN + j]);
    *(u16x8*)(Wxp + (size_t)u*8) = v;
  } else if (t < NT_WX + NT_WH){
    int u = t - NT_WX;
    int lane = u&63; int kb = (u>>6)&31; int nblk = u>>11;
    int col = nblk*16 + (lane&15);
    int k0  = kb*32 + ((lane>>4)<<3);
    int g = col>>10, j = col&1023;
    const float* W = (g==0)?Wf:(g==1)?Wi:(g==2)?Wc:Wo;
    u16x8 v;
    #pragma unroll
    for (int e=0;e<8;e++) v[e] = f2bf(W[(size_t)(EMBED + k0+e)*HIDDEN + j]);
    *(u16x8*)(Whp + (size_t)u*8) = v;
  } else {
    int u = t - NT_WX - NT_WH;
    if (u < GCOLS){
      int g = u>>10, j = u&1023;
      const float* B = (g==0)?bf_:(g==1)?bi_:(g==2)?bc_:bo_;
      bcat[u] = B[j];
    }
  }
}

// ---------------------------------------------------------------------------
__global__ __launch_bounds__(256) void gather_kernel(
    const int* __restrict__ tok, const float* __restrict__ embed, u16* __restrict__ Xg)
{
  int t = blockIdx.x*256 + threadIdx.x;
  int lane = t&63; int kb = (t>>6)&15; int mblk = t>>10;
  int s = mblk; int b = lane&15;
  int token = tok[b*SEQ + s];
  int k0 = kb*32 + ((lane>>4)<<3);
  const float* src = embed + (size_t)token*EMBED + k0;
  u16x8 v;
  #pragma unroll
  for (int e=0;e<8;e++) v[e] = f2bf(src[e]);
  *(u16x8*)(Xg + (size_t)t*8) = v;
}

// ---------------------------------------------------------------------------
template<int KB, bool REMAP>
__global__ __launch_bounds__(256,2) void gemm_pk(
    const u16* __restrict__ Ap, const u16* __restrict__ Bp,
    const float* __restrict__ bias, float* __restrict__ C,
    int Nblk128, int N)
{
  __shared__ u16 sm[8192];
  int tid = threadIdx.x; int lane = tid&63; int wv = tid>>6;
  int nwg = gridDim.x;
  int bid = blockIdx.x;
  int swz = (bid&7)*(nwg>>3) + (bid>>3);
  int bm = swz / Nblk128, bn = swz % Nblk128;
  int wr = wv>>1, wc = wv&1;
  f32x4 acc[4][4] = {};
  const u16* Abase = Ap + (size_t)(bm*8)*KB*512;
  const u16* Bbase = Bp + (size_t)(bn*8)*KB*512;
  for (int kb=0; kb<KB; ++kb){
    __syncthreads();
    #pragma unroll
    for (int c2=0;c2<4;c2++){
      int chunk = wv*4 + c2;
      const u16* g;
      if (chunk < 8) g = Abase + ((size_t)chunk*KB + kb)*512 + lane*8;
      else           g = Bbase + ((size_t)(chunk-8)*KB + kb)*512 + lane*8;
      gload_lds16(g, sm + chunk*512);
    }
    __syncthreads();
    bf16x8 a[4], b[4];
    #pragma unroll
    for (int m=0;m<4;m++) a[m] = *(const bf16x8*)(sm + (wr*4+m)*512 + lane*8);
    #pragma unroll
    for (int n=0;n<4;n++) b[n] = *(const bf16x8*)(sm + 4096 + (wc*4+n)*512 + lane*8);
    #pragma unroll
    for (int m=0;m<4;m++)
      #pragma unroll
      for (int n=0;n<4;n++)
        acc[m][n] = __builtin_amdgcn_mfma_f32_16x16x32_bf16(a[m], b[n], acc[m][n], 0,0,0);
  }
  int colb = bn*128 + wc*64;
  int rowb = bm*128 + wr*64;
  #pragma unroll
  for (int m=0;m<4;m++){
    int row0 = rowb + m*16 + (lane>>4)*4;
    #pragma unroll
    for (int n=0;n<4;n++){
      int col = colb + n*16 + (lane&15);
      float bv = bias[col];
      #pragma unroll
      for (int r2=0;r2<4;r2++){
        int row = row0 + r2;
        int orow = REMAP ? ((row&15)*SEQ + (row>>4)) : row;
        C[(size_t)orow*N + col] = acc[m][n][r2] + bv;
      }
    }
  }
}

// ---------------------------------------------------------------------------
// FUSED. Recurrence = r10 structure + CANARY-HINTED poll: consumers spin on
// 16 canary words/wave (private 128B lines, ~30x less poll L3 traffic than
// data-polling — the r7-r11 invariant pacer suspect), then read h data ONCE;
// data sentinels remain the correctness net (canary is only a hint, so no
// producer-side store ordering is needed). GEMM pool: 8-buffer deep pipeline
// (7-ahead staging, counted per-wave vmcnt, barrier publishes cross-wave).
// ---------------------------------------------------------------------------
__global__ __launch_bounds__(256,1) void lstm_fused(
    const u16* __restrict__ Whp, const float* __restrict__ Xpre,
    u16* hb, u16* Hp, u32* cnt, u32* tix, u32* packdone, u32* canary,
    const float* __restrict__ Wout, u16* __restrict__ Woutp,
    const float* __restrict__ bout, float* __restrict__ out)
{
  __shared__ char SMEM[148480];
  __shared__ u32 s_tick;
  u16* smWf = (u16*)SMEM;
  float (*gl)[16][17] = (float (*)[16][17])(SMEM + 131072);
  u16* smg = (u16*)SMEM;             // GEMM phase: 8 x 8KB buffers

  int tid = threadIdx.x; int lane = tid&63; int v = tid>>6;
  int w = blockIdx.x;

  if (w >= NWREC){
    // ---------------- Wout pack (L3-direct stores) ------------------------
    const int NPK = (VOCAB/16)*(HIDDEN/32)*64;
    int u0 = (w - NWREC)*256 + tid;
    for (int u = u0; u < NPK; u += NWPACK*256){
      int l = u&63; int kb = (u>>6)&31; int nblk = u>>11;
      int col = nblk*16 + (l&15);
      int k0  = kb*32 + ((l>>4)<<3);
      u16x8 vv;
      #pragma unroll
      for (int e=0;e<8;e++) vv[e] = f2bf(Wout[(size_t)(k0+e)*VOCAB + col]);
      u64x2 t2 = __builtin_bit_cast(u64x2, vv);
      u64* dst = (u64*)(Woutp + (size_t)u*8);
      as64(dst+0, t2[0]);
      as64(dst+1, t2[1]);
    }
    asm volatile("s_waitcnt vmcnt(0)" ::: "memory");
    __syncthreads();
    if (tid==0) (void)__hip_atomic_fetch_add(packdone, 1u,
                       __ATOMIC_RELAXED, __HIP_MEMORY_SCOPE_AGENT);
  } else {
    // ---------------- recurrence ------------------------------------------
    #pragma unroll
    for (int f=0; f<32; ++f){
      int frag = v*32 + f;
      int g = frag>>5, kc = frag&31;
      const u16* src = Whp + ((size_t)(g*64 + w)*32 + kc)*512 + lane*8;
      gload_lds16(src, smWf + (size_t)frag*512);
    }
    asm volatile("s_waitcnt vmcnt(0)" ::: "memory");
    __syncthreads();

    float c = 0.f;
    int pb = tid>>4, pj = tid&15;
    int j = w*16 + pj;
    const int a_row = lane&15, a_k = (lane>>4)*8;
    const float* xb0 = Xpre + (size_t)pb*GCOLS + j;
    float x0 = xb0[0], x1 = xb0[1024], x2 = xb0[2048], x3 = xb0[3072];

    for (int s=0;s<SEQ;s++){
      const u16* rbuf = hb + (size_t)s*16384;
      // --- canary-hinted poll: spin on 16 private hint lines, read data once
      const u32* cyp = canary + ((size_t)s*64 + (size_t)v*16 + (lane&15))*32;
      u64 vv[16];
      {
        // optimistic combined first try (data + canary in flight together)
        #pragma unroll
        for (int i=0;i<16;i++){
          const u64* p = (const u64*)(rbuf + a_row*1024 + (v*8+(i>>1))*32 + a_k) + (i&1);
          vv[i] = al64(p);
        }
        u32 cv = al32(cyp);
        if (!__all(cv != 0u)){
          do { __builtin_amdgcn_s_sleep(1); cv = al32(cyp); } while (!__all(cv != 0u));
          #pragma unroll
          for (int i=0;i<16;i++){
            const u64* p = (const u64*)(rbuf + a_row*1024 + (v*8+(i>>1))*32 + a_k) + (i&1);
            vv[i] = al64(p);
          }
        }
        for(;;){
          bool ok = true;
          #pragma unroll
          for (int i=0;i<16;i++)
            ok &= ((u32)vv[i]!=SENT32) & ((u32)(vv[i]>>32)!=SENT32);
          if (ok) break;                         // canary is a hint; data is truth
          __builtin_amdgcn_s_sleep(0);
          #pragma unroll
          for (int i=0;i<16;i++){
            const u64* p = (const u64*)(rbuf + a_row*1024 + (v*8+(i>>1))*32 + a_k) + (i&1);
            vv[i] = al64(p);
          }
        }
      }
      // x prefetch for s+1
      float xn0=0.f,xn1=0.f,xn2=0.f,xn3=0.f;
      if (s < SEQ-1){
        const float* xn = Xpre + ((size_t)(s+1)*16 + pb)*GCOLS + j;
        xn0 = xn[0]; xn1 = xn[1024]; xn2 = xn[2048]; xn3 = xn[3072];
      }
      // MFMA
      bf16x8 af[8];
      #pragma unroll
      for (int i=0;i<8;i++){
        u64x2 t2 = {vv[2*i], vv[2*i+1]};
        af[i] = __builtin_bit_cast(bf16x8, t2);
      }
      f32x4 acc[4] = {};
      #pragma unroll
      for (int i=0;i<8;i++){
        #pragma unroll
        for (int g=0;g<4;g++){
          bf16x8 wfv = *(const bf16x8*)(smWf + ((size_t)(g*32 + v*8 + i))*512 + lane*8);
          acc[g] = __builtin_amdgcn_mfma_f32_16x16x32_bf16(af[i], wfv, acc[g], 0,0,0);
        }
      }
      {
        int jj = lane&15, b0 = (lane>>4)*4;
        #pragma unroll
        for (int g=0;g<4;g++)
          #pragma unroll
          for (int r2=0;r2<4;r2++)
            gl[v*4+g][b0+r2][jj] = acc[g][r2];
      }
      // B1: LDS drain + raw barrier (NO vmcnt drain)
      asm volatile("s_waitcnt lgkmcnt(0)" ::: "memory");
      __builtin_amdgcn_s_barrier();
      __builtin_amdgcn_sched_barrier(0);
      float p0 = x0 + gl[0][pb][pj] + gl[4][pb][pj] + gl[ 8][pb][pj] + gl[12][pb][pj];
      float p1 = x1 + gl[1][pb][pj] + gl[5][pb][pj] + gl[ 9][pb][pj] + gl[13][pb][pj];
      float p2 = x2 + gl[2][pb][pj] + gl[6][pb][pj] + gl[10][pb][pj] + gl[14][pb][pj];
      float p3 = x3 + gl[3][pb][pj] + gl[7][pb][pj] + gl[11][pb][pj] + gl[15][pb][pj];
      float fg = 1.f/(1.f+__expf(-p0));
      float ig = 1.f/(1.f+__expf(-p1));
      float e2 = __expf(2.f*fminf(fmaxf(p2,-15.f),15.f));
      float cand = (e2-1.f)/(e2+1.f);
      float og = 1.f/(1.f+__expf(-p3));
      c = c*fg + cand*ig;
      float h = c*og;
      x0 = xn0; x1 = xn1; x2 = xn2; x3 = xn3;
      u32 hw_ = (u32)f2bf(h);
      u32 ow_ = (u32)__shfl_xor((int)hw_, 1);
      if ((pj&1)==0){
        u32 word = hw_ | (ow_<<16);
        if (s < SEQ-1){
          u16* wstep = hb + (size_t)(s+1)*16384;
          as32((u32*)wstep + (size_t)pb*512 + w*8 + (pj>>1), word);  // fire & forget
        }
        as32((u32*)Hp + (size_t)s*8192 + (size_t)(j>>5)*256
                      + (size_t)(((j>>3)&3)*16 + pb)*4 + ((j&7)>>1), word);
      }
      // B2: raw barrier (gl WAR + all h stores issued)
      __builtin_amdgcn_s_barrier();
      __builtin_amdgcn_sched_barrier(0);
      // canary hint for step s+1 consumers (no ordering required)
      if (tid==0 && s < SEQ-1)
        as32(canary + ((size_t)(s+1)*64 + w)*32, 1u);
      if ((s&7)==7){
        asm volatile("s_waitcnt vmcnt(0)" ::: "memory");
        __builtin_amdgcn_s_barrier();
        asm volatile("" ::: "memory");
        if (tid==0)
          (void)__hip_atomic_fetch_add(cnt + (size_t)(s>>3)*16, 1u,
                   __ATOMIC_RELAXED, __HIP_MEMORY_SCOPE_AGENT);
      }
    }
  }

  // ---------------- logits-GEMM worker pool -------------------------------
  if (tid==0){
    while (al32(packdone) < (u32)NWPACK) __builtin_amdgcn_s_sleep(8);
  }
  __syncthreads();

  int wv = tid>>6;
  int wr = wv>>1, wc = wv&1;
  for(;;){
    __syncthreads();
    if (tid==0) s_tick = __hip_atomic_fetch_add(tix, 1u,
                   __ATOMIC_RELAXED, __HIP_MEMORY_SCOPE_AGENT);
    __syncthreads();
    u32 t = s_tick;
    if (t >= (u32)NTILE) break;
    u32 rr = t / 1000u, local = t % 1000u;
    int bn = (int)(local >> 2);
    int bm = (int)(rr*4u + (local & 3u));
    if (tid==0){
      while (al32(cnt + (size_t)bm*16) < (u32)NWREC)
        __builtin_amdgcn_s_sleep(8);
    }
    __syncthreads();                                 // full drain
    const u16* Ab = Hp + (size_t)(bm*8)*32*512;
    const u16* Bb = Woutp + (size_t)(bn*8)*32*512;
    auto stage = [&](int kb, int bi){
      #pragma unroll
      for (int c2=0;c2<4;c2++){
        int chunk = wv*4 + c2;
        const u16* g;
        if (chunk < 8) g = Ab + ((size_t)chunk*32 + kb)*512 + lane*8;
        else           g = Bb + ((size_t)(chunk-8)*32 + kb)*512 + lane*8;
        gload_lds16(g, smg + (size_t)bi*8192 + chunk*512);
      }
    };
    // 8-slot pipeline, 7 buffers staged ahead (28 loads/wave in flight)
    #pragma unroll
    for (int k=0;k<7;k++) stage(k, k);
    f32x4 acc[4][4] = {};
    for (int kb=0; kb<32; ++kb){
      if      (kb <= 25) asm volatile("s_waitcnt vmcnt(24)" ::: "memory");
      else if (kb == 26) asm volatile("s_waitcnt vmcnt(20)" ::: "memory");
      else if (kb == 27) asm volatile("s_waitcnt vmcnt(16)" ::: "memory");
      else if (kb == 28) asm volatile("s_waitcnt vmcnt(12)" ::: "memory");
      else if (kb == 29) asm volatile("s_waitcnt vmcnt(8)"  ::: "memory");
      else if (kb == 30) asm volatile("s_waitcnt vmcnt(4)"  ::: "memory");
      else               asm volatile("s_waitcnt vmcnt(0)"  ::: "memory");
      __builtin_amdgcn_s_barrier();                  // publish staged kb (all waves)
      if (kb <= 24) stage(kb+7, (kb+7)&7);
      const u16* bufp = smg + (size_t)(kb&7)*8192;
      bf16x8 a[4], b[4];
      #pragma unroll
      for (int m=0;m<4;m++) a[m] = *(const bf16x8*)(bufp + (wr*4+m)*512 + lane*8);
      #pragma unroll
      for (int n=0;n<4;n++) b[n] = *(const bf16x8*)(bufp + 4096 + (wc*4+n)*512 + lane*8);
      #pragma unroll
      for (int m=0;m<4;m++)
        #pragma unroll
        for (int n=0;n<4;n++)
          acc[m][n] = __builtin_amdgcn_mfma_f32_16x16x32_bf16(a[m], b[n], acc[m][n], 0,0,0);
    }
    int colb = bn*128 + wc*64;
    int rowb = bm*128 + wr*64;
    #pragma unroll
    for (int m=0;m<4;m++){
      int row0 = rowb + m*16 + (lane>>4)*4;
      #pragma unroll
      for (int n=0;n<4;n++){
        int col = colb + n*16 + (lane&15);
        float bv = bout[col];
        #pragma unroll
        for (int r2=0;r2<4;r2++){
          int row = row0 + r2;
          int orow = (row&15)*SEQ + (row>>4);
          __builtin_nontemporal_store(acc[m][n][r2] + bv,
                                      &out[(size_t)orow*VOCAB + col]);
        }
      }
    }
  }
}

// ---------------------------------------------------------------------------
extern "C" void kernel_launch(void* const* d_in, const int* in_sizes, int n_in,
                              void* d_out, int out_size, void* d_ws, size_t ws_size,
                              hipStream_t stream)
{
  (void)in_sizes; (void)n_in; (void)out_size; (void)ws_size;
  const int*   tok   = (const int*)d_in[0];
  const float* embed = (const float*)d_in[1];
  const float* Wf    = (const float*)d_in[2];
  const float* bf_   = (const float*)d_in[3];
  const float* Wi    = (const float*)d_in[4];
  const float* bi_   = (const float*)d_in[5];
  const float* Wc    = (const float*)d_in[6];
  const float* bc_   = (const float*)d_in[7];
  const float* Wo    = (const float*)d_in[8];
  const float* bo_   = (const float*)d_in[9];
  const float* Wout  = (const float*)d_in[10];
  const float* bout  = (const float*)d_in[11];
  float* out = (float*)d_out;

  char* ws = (char*)d_ws;
  size_t off = 0;
  auto alloc = [&](size_t bytes)->void*{
    void* p = ws + off; off += (bytes + 255) & ~(size_t)255; return p;
  };
  // dead-after-gemm16 region; hb aliases it (memset AFTER gemm16):
  u16*  Wxp   = (u16*)alloc((size_t)2097152*2);        // 4 MB
  u16*  Xg    = (u16*)alloc((size_t)2097152*2);        // 4 MB
  float* bcat = (float*)alloc((size_t)4096*4);         // 16 KB
  u16*  hb    = (u16*)ws;                              // 256 x 32KB = 8 MB alias
  // live-through-fused region:
  u16*  Whp   = (u16*)alloc((size_t)4194304*2);        // 8 MB
  u16*  Woutp = (u16*)alloc((size_t)32768000*2);       // 65.5 MB
  float* Xpre = (float*)alloc((size_t)NROW*GCOLS*4);   // 64 MB
  u16*  Hp    = (u16*)alloc((size_t)4194304*2);        // 8 MB
  u32*  cnt   = (u32*)alloc((size_t)4096);             // 32 bm x 64B
  u32*  tix   = (u32*)alloc((size_t)256);
  u32*  packdone = (u32*)alloc((size_t)256);
  u32*  canary = (u32*)alloc((size_t)SEQ*64*128);      // 2 MB: [step][prod] 128B lines

  pack_gates<<<3088, 256, 0, stream>>>(Wf,Wi,Wc,Wo, bf_,bi_,bc_,bo_,
                                       Wxp, Whp, bcat);
  gather_kernel<<<1024, 256, 0, stream>>>(tok, embed, Xg);
  gemm_pk<16,false><<<1024, 256, 0, stream>>>(Xg, Wxp, bcat, Xpre, 32, GCOLS);
  // hb aliases Wxp/Xg -> init only after gemm16:
  (void)hipMemsetAsync(hb, 0x00, 32768, stream);                    // h_0 = 0
  (void)hipMemsetAsync((char*)hb + 32768, 0xFF, 255*32768, stream); // sentinels
  (void)hipMemsetAsync(cnt, 0, 4096 + 256 + 256, stream);
  (void)hipMemsetAsync(canary, 0x01, 64*128, stream);               // step-0 hints set
  (void)hipMemsetAsync((char*)canary + 64*128, 0x00, (SEQ-1)*64*128, stream);
  lstm_fused<<<NWREC+NWPACK, 256, 0, stream>>>(Whp, Xpre, hb, Hp, cnt, tix,
                                               packdone, canary, Wout, Woutp, bout, out);
}

// Round 13
// 1245.819 us; speedup vs baseline: 1.7556x; 1.1654x over previous
//
#include <hip/hip_runtime.h>
#include <hip/hip_bf16.h>

#define VOCAB  32000
#define EMBED  512
#define HIDDEN 1024
#define BATCH  16
#define SEQ    256
#define NROW   (BATCH*SEQ)
#define GCOLS  (4*HIDDEN)
#define NWREC  64
#define NWPACK 192
#define NTILE  8000          // 8 rounds x (250 bn x 4 bm)
#define SENT32 0xFFFFFFFFu

typedef unsigned short u16;
typedef unsigned int   u32;
typedef unsigned long long u64;
typedef __attribute__((ext_vector_type(4))) float f32x4;
typedef __attribute__((ext_vector_type(8))) short bf16x8;
typedef __attribute__((ext_vector_type(8))) unsigned short u16x8;
typedef __attribute__((ext_vector_type(2))) unsigned long long u64x2;

__device__ inline u16 f2bf(float f){
  __hip_bfloat16 h = __float2bfloat16(f);
  return __builtin_bit_cast(u16, h);
}
__device__ inline void gload_lds16(const void* g, void* l){
  __builtin_amdgcn_global_load_lds((const __attribute__((address_space(1))) u32*)g,
                                   (__attribute__((address_space(3))) u32*)l, 16, 0, 0);
}
__device__ __forceinline__ u32 al32(const u32* p){
  return __hip_atomic_load(p, __ATOMIC_RELAXED, __HIP_MEMORY_SCOPE_AGENT);
}
__device__ __forceinline__ void as64(u64* p, u64 v){
  __hip_atomic_store(p, v, __ATOMIC_RELAXED, __HIP_MEMORY_SCOPE_AGENT);
}
// h-exchange: SYSTEM scope -> strongest cache-bypass encoding on both sides.
// Tests the r7-r12 invariant (~4us visibility = relaxed-agent cache dwell).
__device__ __forceinline__ u64 al64_sys(const u64* p){
  return __hip_atomic_load(p, __ATOMIC_RELAXED, __HIP_MEMORY_SCOPE_SYSTEM);
}
__device__ __forceinline__ void as32_sys(u32* p, u32 v){
  __hip_atomic_store(p, v, __ATOMIC_RELAXED, __HIP_MEMORY_SCOPE_SYSTEM);
}
__device__ __forceinline__ void as32(u32* p, u32 v){
  __hip_atomic_store(p, v, __ATOMIC_RELAXED, __HIP_MEMORY_SCOPE_AGENT);
}

// ---------------------------------------------------------------------------
__global__ __launch_bounds__(256) void pack_gates(
    const float* __restrict__ Wf, const float* __restrict__ Wi,
    const float* __restrict__ Wc, const float* __restrict__ Wo,
    const float* __restrict__ bf_, const float* __restrict__ bi_,
    const float* __restrict__ bc_, const float* __restrict__ bo_,
    u16* __restrict__ Wxp, u16* __restrict__ Whp, float* __restrict__ bcat)
{
  const int NT_WX = (GCOLS/16)*(EMBED/32)*64;
  const int NT_WH = (GCOLS/16)*(HIDDEN/32)*64;
  int t = blockIdx.x*256 + threadIdx.x;
  if (t < NT_WX){
    int u = t;
    int lane = u&63; int kb = (u>>6)&15; int nblk = u>>10;
    int col = nblk*16 + (lane&15);
    int k0  = kb*32 + ((lane>>4)<<3);
    int g = col>>10, j = col&1023;
    const float* W = (g==0)?Wf:(g==1)?Wi:(g==2)?Wc:Wo;
    u16x8 v;
    #pragma unroll
    for (int e=0;e<8;e++) v[e] = f2bf(W[(size_t)(k0+e)*HIDDEN + j]);
    *(u16x8*)(Wxp + (size_t)u*8) = v;
  } else if (t < NT_WX + NT_WH){
    int u = t - NT_WX;
    int lane = u&63; int kb = (u>>6)&31; int nblk = u>>11;
    int col = nblk*16 + (lane&15);
    int k0  = kb*32 + ((lane>>4)<<3);
    int g = col>>10, j = col&1023;
    const float* W = (g==0)?Wf:(g==1)?Wi:(g==2)?Wc:Wo;
    u16x8 v;
    #pragma unroll
    for (int e=0;e<8;e++) v[e] = f2bf(W[(size_t)(EMBED + k0+e)*HIDDEN + j]);
    *(u16x8*)(Whp + (size_t)u*8) = v;
  } else {
    int u = t - NT_WX - NT_WH;
    if (u < GCOLS){
      int g = u>>10, j = u&1023;
      const float* B = (g==0)?bf_:(g==1)?bi_:(g==2)?bc_:bo_;
      bcat[u] = B[j];
    }
  }
}

// ---------------------------------------------------------------------------
__global__ __launch_bounds__(256) void gather_kernel(
    const int* __restrict__ tok, const float* __restrict__ embed, u16* __restrict__ Xg)
{
  int t = blockIdx.x*256 + threadIdx.x;
  int lane = t&63; int kb = (t>>6)&15; int mblk = t>>10;
  int s = mblk; int b = lane&15;
  int token = tok[b*SEQ + s];
  int k0 = kb*32 + ((lane>>4)<<3);
  const float* src = embed + (size_t)token*EMBED + k0;
  u16x8 v;
  #pragma unroll
  for (int e=0;e<8;e++) v[e] = f2bf(src[e]);
  *(u16x8*)(Xg + (size_t)t*8) = v;
}

// ---------------------------------------------------------------------------
template<int KB, bool REMAP>
__global__ __launch_bounds__(256,2) void gemm_pk(
    const u16* __restrict__ Ap, const u16* __restrict__ Bp,
    const float* __restrict__ bias, float* __restrict__ C,
    int Nblk128, int N)
{
  __shared__ u16 sm[8192];
  int tid = threadIdx.x; int lane = tid&63; int wv = tid>>6;
  int nwg = gridDim.x;
  int bid = blockIdx.x;
  int swz = (bid&7)*(nwg>>3) + (bid>>3);
  int bm = swz / Nblk128, bn = swz % Nblk128;
  int wr = wv>>1, wc = wv&1;
  f32x4 acc[4][4] = {};
  const u16* Abase = Ap + (size_t)(bm*8)*KB*512;
  const u16* Bbase = Bp + (size_t)(bn*8)*KB*512;
  for (int kb=0; kb<KB; ++kb){
    __syncthreads();
    #pragma unroll
    for (int c2=0;c2<4;c2++){
      int chunk = wv*4 + c2;
      const u16* g;
      if (chunk < 8) g = Abase + ((size_t)chunk*KB + kb)*512 + lane*8;
      else           g = Bbase + ((size_t)(chunk-8)*KB + kb)*512 + lane*8;
      gload_lds16(g, sm + chunk*512);
    }
    __syncthreads();
    bf16x8 a[4], b[4];
    #pragma unroll
    for (int m=0;m<4;m++) a[m] = *(const bf16x8*)(sm + (wr*4+m)*512 + lane*8);
    #pragma unroll
    for (int n=0;n<4;n++) b[n] = *(const bf16x8*)(sm + 4096 + (wc*4+n)*512 + lane*8);
    #pragma unroll
    for (int m=0;m<4;m++)
      #pragma unroll
      for (int n=0;n<4;n++)
        acc[m][n] = __builtin_amdgcn_mfma_f32_16x16x32_bf16(a[m], b[n], acc[m][n], 0,0,0);
  }
  int colb = bn*128 + wc*64;
  int rowb = bm*128 + wr*64;
  #pragma unroll
  for (int m=0;m<4;m++){
    int row0 = rowb + m*16 + (lane>>4)*4;
    #pragma unroll
    for (int n=0;n<4;n++){
      int col = colb + n*16 + (lane&15);
      float bv = bias[col];
      #pragma unroll
      for (int r2=0;r2<4;r2++){
        int row = row0 + r2;
        int orow = REMAP ? ((row&15)*SEQ + (row>>4)) : row;
        C[(size_t)orow*N + col] = acc[m][n][r2] + bv;
      }
    }
  }
}

// ---------------------------------------------------------------------------
// FUSED: r10 chassis, SINGLE change — h exchange uses SYSTEM-scope atomics
// (cache-bypass both sides). Everything else identical to the 1169us r10.
// ---------------------------------------------------------------------------
__global__ __launch_bounds__(256,1) void lstm_fused(
    const u16* __restrict__ Whp, const float* __restrict__ Xpre,
    u16* hb, u16* Hp, u32* cnt, u32* tix, u32* packdone,
    const float* __restrict__ Wout, u16* __restrict__ Woutp,
    const float* __restrict__ bout, float* __restrict__ out)
{
  __shared__ char SMEM[148480];
  __shared__ u32 s_tick;
  u16* smWf = (u16*)SMEM;
  float (*gl)[16][17] = (float (*)[16][17])(SMEM + 131072);
  u16* smg = (u16*)SMEM;             // GEMM phase: 3 x 16KB buffers

  int tid = threadIdx.x; int lane = tid&63; int v = tid>>6;
  int w = blockIdx.x;

  if (w >= NWREC){
    // ---------------- Wout pack (L3-direct stores) ------------------------
    const int NPK = (VOCAB/16)*(HIDDEN/32)*64;
    int u0 = (w - NWREC)*256 + tid;
    for (int u = u0; u < NPK; u += NWPACK*256){
      int l = u&63; int kb = (u>>6)&31; int nblk = u>>11;
      int col = nblk*16 + (l&15);
      int k0  = kb*32 + ((l>>4)<<3);
      u16x8 vv;
      #pragma unroll
      for (int e=0;e<8;e++) vv[e] = f2bf(Wout[(size_t)(k0+e)*VOCAB + col]);
      u64x2 t2 = __builtin_bit_cast(u64x2, vv);
      u64* dst = (u64*)(Woutp + (size_t)u*8);
      as64(dst+0, t2[0]);
      as64(dst+1, t2[1]);
    }
    asm volatile("s_waitcnt vmcnt(0)" ::: "memory");
    __syncthreads();
    if (tid==0) (void)__hip_atomic_fetch_add(packdone, 1u,
                       __ATOMIC_RELAXED, __HIP_MEMORY_SCOPE_AGENT);
  } else {
    // ---------------- recurrence ------------------------------------------
    #pragma unroll
    for (int f=0; f<32; ++f){
      int frag = v*32 + f;
      int g = frag>>5, kc = frag&31;
      const u16* src = Whp + ((size_t)(g*64 + w)*32 + kc)*512 + lane*8;
      gload_lds16(src, smWf + (size_t)frag*512);
    }
    asm volatile("s_waitcnt vmcnt(0)" ::: "memory");
    __syncthreads();

    float c = 0.f;
    int pb = tid>>4, pj = tid&15;
    int j = w*16 + pj;
    const int a_row = lane&15, a_k = (lane>>4)*8;
    const float* xb0 = Xpre + (size_t)pb*GCOLS + j;
    float x0 = xb0[0], x1 = xb0[1024], x2 = xb0[2048], x3 = xb0[3072];

    for (int s=0;s<SEQ;s++){
      const u16* rbuf = hb + (size_t)s*16384;
      // --- data-sentinel poll via SYSTEM-scope loads (cache-bypass) ---
      u64 vv[16];
      for(;;){
        #pragma unroll
        for (int i=0;i<16;i++){
          const u64* p = (const u64*)(rbuf + a_row*1024 + (v*8+(i>>1))*32 + a_k) + (i&1);
          vv[i] = al64_sys(p);
        }
        bool ok = true;
        #pragma unroll
        for (int i=0;i<16;i++)
          ok &= ((u32)vv[i]!=SENT32) & ((u32)(vv[i]>>32)!=SENT32);
        if (ok) break;
        __builtin_amdgcn_s_sleep(1);
      }
      bf16x8 af[8];
      #pragma unroll
      for (int i=0;i<8;i++){
        u64x2 t2 = {vv[2*i], vv[2*i+1]};
        af[i] = __builtin_bit_cast(bf16x8, t2);
      }
      f32x4 acc[4] = {};
      #pragma unroll
      for (int i=0;i<8;i++){
        #pragma unroll
        for (int g=0;g<4;g++){
          bf16x8 wfv = *(const bf16x8*)(smWf + ((size_t)(g*32 + v*8 + i))*512 + lane*8);
          acc[g] = __builtin_amdgcn_mfma_f32_16x16x32_bf16(af[i], wfv, acc[g], 0,0,0);
        }
      }
      {
        int jj = lane&15, b0 = (lane>>4)*4;
        #pragma unroll
        for (int g=0;g<4;g++)
          #pragma unroll
          for (int r2=0;r2<4;r2++)
            gl[v*4+g][b0+r2][jj] = acc[g][r2];
      }
      // B1: LDS-only drain + RAW barrier (NO vmcnt drain)
      asm volatile("s_waitcnt lgkmcnt(0)" ::: "memory");
      __builtin_amdgcn_s_barrier();
      __builtin_amdgcn_sched_barrier(0);
      // x-prefetch for s+1 (independent; overlaps pointwise + next poll)
      float xn0=0.f,xn1=0.f,xn2=0.f,xn3=0.f;
      if (s < SEQ-1){
        const float* xn = Xpre + ((size_t)(s+1)*16 + pb)*GCOLS + j;
        xn0 = xn[0]; xn1 = xn[1024]; xn2 = xn[2048]; xn3 = xn[3072];
      }
      float p0 = x0 + gl[0][pb][pj] + gl[4][pb][pj] + gl[ 8][pb][pj] + gl[12][pb][pj];
      float p1 = x1 + gl[1][pb][pj] + gl[5][pb][pj] + gl[ 9][pb][pj] + gl[13][pb][pj];
      float p2 = x2 + gl[2][pb][pj] + gl[6][pb][pj] + gl[10][pb][pj] + gl[14][pb][pj];
      float p3 = x3 + gl[3][pb][pj] + gl[7][pb][pj] + gl[11][pb][pj] + gl[15][pb][pj];
      float fg = 1.f/(1.f+__expf(-p0));
      float ig = 1.f/(1.f+__expf(-p1));
      float e2 = __expf(2.f*fminf(fmaxf(p2,-15.f),15.f));
      float cand = (e2-1.f)/(e2+1.f);
      float og = 1.f/(1.f+__expf(-p3));
      c = c*fg + cand*ig;
      float h = c*og;
      x0 = xn0; x1 = xn1; x2 = xn2; x3 = xn3;
      u32 hw_ = (u32)f2bf(h);
      u32 ow_ = (u32)__shfl_xor((int)hw_, 1);
      if ((pj&1)==0){
        u32 word = hw_ | (ow_<<16);
        if (s < SEQ-1){
          u16* wstep = hb + (size_t)(s+1)*16384;
          as32_sys((u32*)wstep + (size_t)pb*512 + w*8 + (pj>>1), word); // write-through
        }
        as32((u32*)Hp + (size_t)s*8192 + (size_t)(j>>5)*256
                      + (size_t)(((j>>3)&3)*16 + pb)*4 + ((j&7)>>1), word);
      }
      // B2: RAW barrier only
      __builtin_amdgcn_s_barrier();
      __builtin_amdgcn_sched_barrier(0);
      if ((s&7)==7){
        // per-8-step bookkeeping: the ONLY store-ack wait on the chain
        asm volatile("s_waitcnt vmcnt(0)" ::: "memory");
        __builtin_amdgcn_s_barrier();
        asm volatile("" ::: "memory");
        if (tid==0)
          (void)__hip_atomic_fetch_add(cnt + (size_t)(s>>3)*16, 1u,
                   __ATOMIC_RELAXED, __HIP_MEMORY_SCOPE_AGENT);
      }
    }
  }

  // ---------------- logits-GEMM worker pool -------------------------------
  if (tid==0){
    while (al32(packdone) < (u32)NWPACK) __builtin_amdgcn_s_sleep(8);
  }
  __syncthreads();

  int wv = tid>>6;
  int wr = wv>>1, wc = wv&1;
  for(;;){
    __syncthreads();
    if (tid==0) s_tick = __hip_atomic_fetch_add(tix, 1u,
                   __ATOMIC_RELAXED, __HIP_MEMORY_SCOPE_AGENT);
    __syncthreads();
    u32 t = s_tick;
    if (t >= (u32)NTILE) break;
    u32 rr = t / 1000u, local = t % 1000u;
    int bn = (int)(local >> 2);
    int bm = (int)(rr*4u + (local & 3u));
    if (tid==0){
      while (al32(cnt + (size_t)bm*16) < (u32)NWREC)
        __builtin_amdgcn_s_sleep(8);
    }
    __syncthreads();                                 // full drain (vm+lgkm)
    const u16* Ab = Hp + (size_t)(bm*8)*32*512;
    const u16* Bb = Woutp + (size_t)(bn*8)*32*512;
    auto stage = [&](int kb, int bi){
      #pragma unroll
      for (int c2=0;c2<4;c2++){
        int chunk = wv*4 + c2;
        const u16* g;
        if (chunk < 8) g = Ab + ((size_t)chunk*32 + kb)*512 + lane*8;
        else           g = Bb + ((size_t)(chunk-8)*32 + kb)*512 + lane*8;
        gload_lds16(g, smg + (size_t)bi*8192 + chunk*512);
      }
    };
    stage(0,0); stage(1,1);
    f32x4 acc[4][4] = {};
    for (int kb=0; kb<32; ++kb){
      if (kb<31) asm volatile("s_waitcnt vmcnt(4)" ::: "memory");
      else       asm volatile("s_waitcnt vmcnt(0)" ::: "memory");
      __builtin_amdgcn_s_barrier();                  // raw: loads stay in flight
      if (kb+2<32) stage(kb+2, (kb+2)%3);
      const u16* bufp = smg + (size_t)(kb%3)*8192;
      bf16x8 a[4], b[4];
      #pragma unroll
      for (int m=0;m<4;m++) a[m] = *(const bf16x8*)(bufp + (wr*4+m)*512 + lane*8);
      #pragma unroll
      for (int n=0;n<4;n++) b[n] = *(const bf16x8*)(bufp + 4096 + (wc*4+n)*512 + lane*8);
      #pragma unroll
      for (int m=0;m<4;m++)
        #pragma unroll
        for (int n=0;n<4;n++)
          acc[m][n] = __builtin_amdgcn_mfma_f32_16x16x32_bf16(a[m], b[n], acc[m][n], 0,0,0);
    }
    int colb = bn*128 + wc*64;
    int rowb = bm*128 + wr*64;
    #pragma unroll
    for (int m=0;m<4;m++){
      int row0 = rowb + m*16 + (lane>>4)*4;
      #pragma unroll
      for (int n=0;n<4;n++){
        int col = colb + n*16 + (lane&15);
        float bv = bout[col];
        #pragma unroll
        for (int r2=0;r2<4;r2++){
          int row = row0 + r2;
          int orow = (row&15)*SEQ + (row>>4);
          __builtin_nontemporal_store(acc[m][n][r2] + bv,
                                      &out[(size_t)orow*VOCAB + col]);
        }
      }
    }
  }
}

// ---------------------------------------------------------------------------
extern "C" void kernel_launch(void* const* d_in, const int* in_sizes, int n_in,
                              void* d_out, int out_size, void* d_ws, size_t ws_size,
                              hipStream_t stream)
{
  (void)in_sizes; (void)n_in; (void)out_size; (void)ws_size;
  const int*   tok   = (const int*)d_in[0];
  const float* embed = (const float*)d_in[1];
  const float* Wf    = (const float*)d_in[2];
  const float* bf_   = (const float*)d_in[3];
  const float* Wi    = (const float*)d_in[4];
  const float* bi_   = (const float*)d_in[5];
  const float* Wc    = (const float*)d_in[6];
  const float* bc_   = (const float*)d_in[7];
  const float* Wo    = (const float*)d_in[8];
  const float* bo_   = (const float*)d_in[9];
  const float* Wout  = (const float*)d_in[10];
  const float* bout  = (const float*)d_in[11];
  float* out = (float*)d_out;

  char* ws = (char*)d_ws;
  size_t off = 0;
  auto alloc = [&](size_t bytes)->void*{
    void* p = ws + off; off += (bytes + 255) & ~(size_t)255; return p;
  };
  // dead-after-gemm16 region; hb aliases it (memset AFTER gemm16):
  u16*  Wxp   = (u16*)alloc((size_t)2097152*2);        // 4 MB
  u16*  Xg    = (u16*)alloc((size_t)2097152*2);        // 4 MB
  float* bcat = (float*)alloc((size_t)4096*4);         // 16 KB
  u16*  hb    = (u16*)ws;                              // 256 x 32KB = 8 MB alias
  // live-through-fused region:
  u16*  Whp   = (u16*)alloc((size_t)4194304*2);        // 8 MB
  u16*  Woutp = (u16*)alloc((size_t)32768000*2);       // 65.5 MB
  float* Xpre = (float*)alloc((size_t)NROW*GCOLS*4);   // 64 MB
  u16*  Hp    = (u16*)alloc((size_t)4194304*2);        // 8 MB
  u32*  cnt   = (u32*)alloc((size_t)4096);             // 32 bm x 64B
  u32*  tix   = (u32*)alloc((size_t)256);
  u32*  packdone = (u32*)alloc((size_t)256);

  pack_gates<<<3088, 256, 0, stream>>>(Wf,Wi,Wc,Wo, bf_,bi_,bc_,bo_,
                                       Wxp, Whp, bcat);
  gather_kernel<<<1024, 256, 0, stream>>>(tok, embed, Xg);
  gemm_pk<16,false><<<1024, 256, 0, stream>>>(Xg, Wxp, bcat, Xpre, 32, GCOLS);
  // hb aliases Wxp/Xg -> init only after gemm16:
  (void)hipMemsetAsync(hb, 0x00, 32768, stream);                    // h_0 = 0
  (void)hipMemsetAsync((char*)hb + 32768, 0xFF, 255*32768, stream); // sentinels
  (void)hipMemsetAsync(cnt, 0, 4096 + 256 + 256, stream);
  lstm_fused<<<NWREC+NWPACK, 256, 0, stream>>>(Whp, Xpre, hb, Hp, cnt, tix,
                                               packdone, Wout, Woutp, bout, out);
}